// Round 1
// baseline (542.347 us; speedup 1.0000x reference)
//
#include <hip/hip_runtime.h>

typedef __attribute__((ext_vector_type(8))) short short8;    // 8 bf16 (4 VGPRs)
typedef __attribute__((ext_vector_type(4))) float float4v;   // 4 fp32 acc

#define CAP 64      // per-node edge bucket capacity (in-degree is Poisson(16), max ~45)
#define NPB 128     // nodes per bin (col-range per pass-2 workgroup)
#define NCHUNK 8    // XCD chunks (blockIdx % 8 ~ XCD round-robin)
#define BINCAP 384  // per-(chunk,bin) capacity: mean 256, sigma 16 -> +8 sigma

__device__ __forceinline__ ushort f2bf(float f) {
    uint u = __float_as_uint(f);
    u += 0x7fffu + ((u >> 16) & 1u);   // round-to-nearest-even
    return (ushort)(u >> 16);
}
__device__ __forceinline__ float bf2f(ushort h) {
    return __uint_as_float((uint)h << 16);
}
__device__ __forceinline__ void acc8(float* acc, uint4 v) {
    acc[0] += __uint_as_float(v.x << 16);
    acc[1] += __uint_as_float(v.x & 0xffff0000u);
    acc[2] += __uint_as_float(v.y << 16);
    acc[3] += __uint_as_float(v.y & 0xffff0000u);
    acc[4] += __uint_as_float(v.z << 16);
    acc[5] += __uint_as_float(v.z & 0xffff0000u);
    acc[6] += __uint_as_float(v.w << 16);
    acc[7] += __uint_as_float(v.w & 0xffff0000u);
}
__device__ __forceinline__ int clampi(int v, int n) {
    return (int)min((uint)v, (uint)(n - 1));
}

// ---------------- zero idg + out + binCnt in one dispatch ----------------
__global__ void zero_all_k(int* __restrict__ idg, float* __restrict__ out,
                           int* __restrict__ binCnt, int n, int nout, int nbc) {
    int i = blockIdx.x * 256 + threadIdx.x;
    if (i < n) idg[i] = 0;
    if (i < nout) out[i] = 0.f;
    if (i < nbc) binCnt[i] = 0;
}

// ---------------- pass 1: XCD-local binning of edges ----------------
// chunk = blockIdx%8 tracks round-robin block->XCD dispatch, so each
// (chunk,bin) append stream is written by ONE XCD's L2 -> full-line flushes.
// binBuf layout: cell = chunk*nbins + bin, so each chunk's 2.4 MB region is
// L2-resident on its XCD during the pass.
__global__ void fillbin1_k(const int* __restrict__ row, const int* __restrict__ col,
                           int* __restrict__ idg, int* __restrict__ eidx,
                           int* __restrict__ binCnt, int2* __restrict__ binBuf,
                           int E, int nbins) {
    int e = blockIdx.x * 256 + threadIdx.x;
    int chunk = blockIdx.x & (NCHUNK - 1);
    if (e < E) {
        int c = col[e], r = row[e];
        int b = c >> 7;                               // c / NPB
        int cell = chunk * nbins + b;
        int p = atomicAdd(&binCnt[cell], 1);
        if (p < BINCAP) {
            binBuf[(size_t)cell * BINCAP + p] = make_int2(r, c);
        } else {                                      // overflow fallback: old direct path
            int q = atomicAdd(&idg[c], 1);
            if (q < CAP) eidx[(size_t)c * CAP + q] = r;
        }
    }
}

// ---------------- pass 2: drain bins -> bucketed CSR, single-L2 scatter ----------------
// one block per bin (128-node range -> 32 KB eidx window); wave w drains chunk w.
// All scatter writes for a given eidx line come from one workgroup -> dirty-once.
__global__ __launch_bounds__(512) void fillbin2_k(const int* __restrict__ binCnt,
                                                  const int2* __restrict__ binBuf,
                                                  int* __restrict__ idg,
                                                  int* __restrict__ eidx, int nbins) {
    int bin = blockIdx.x;
    int wv = threadIdx.x >> 6, lane = threadIdx.x & 63;
    int cell = wv * nbins + bin;
    int n = min(binCnt[cell], BINCAP);
    const int2* bp = binBuf + (size_t)cell * BINCAP;
    for (int j = lane; j < n; j += 64) {
        int2 pr = bp[j];
        int c = pr.y;
        int p = atomicAdd(&idg[c], 1);
        if (p < CAP) eidx[(size_t)c * CAP + p] = pr.x;
    }
}

// ---------------- fused: pack W1+W2 to MFMA B-frag order, and x -> bf16*dinv ----------------
// dinv computed inline from idg (no dinv array anywhere in the pipeline)
__global__ void prep_k(const float* __restrict__ W1, ushort* __restrict__ W1p,
                       const float* __restrict__ W2, ushort* __restrict__ W2p,
                       const float* __restrict__ x, const int* __restrict__ idg,
                       ushort* __restrict__ xb, int n4) {
    int idx = blockIdx.x * 256 + threadIdx.x;
    if (idx < 32768) {                       // pack W1 (S=4)
        int j = idx & 7, lane = (idx >> 3) & 63;
        int s = (idx >> 9) % 4, nt = (idx >> 9) / 4;
        int k = 32 * s + (lane >> 4) * 8 + j;
        int c = nt * 16 + (lane & 15);
        W1p[idx] = f2bf(W1[k * 256 + c]);
    } else if (idx < 32768 + 65536) {        // pack W2 (S=8)
        int q = idx - 32768;
        int j = q & 7, lane = (q >> 3) & 63;
        int s = (q >> 9) % 8, nt = (q >> 9) / 8;
        int k = 32 * s + (lane >> 4) * 8 + j;
        int c = nt * 16 + (lane & 15);
        W2p[q] = f2bf(W2[k * 256 + c]);
    } else {                                 // cvt: x fp32 -> bf16 * dinv
        int i = idx - (32768 + 65536);
        if (i < n4) {
            int node = i >> 5;               // 32 float4 per 128-dim row
            float di = rsqrtf((float)(idg[node] + 1));
            float4 v = ((const float4*)x)[i];
            ushort4 o;
            o.x = f2bf(v.x * di); o.y = f2bf(v.y * di);
            o.z = f2bf(v.z * di); o.w = f2bf(v.w * di);
            ((ushort4*)xb)[i] = o;
        }
    }
}

// ---------------- agg, 128-dim rows: out[i] = dinv[i]*(g[i] + sum g[src]) ----------------
__global__ __launch_bounds__(256) void agg128_k(const ushort* __restrict__ g,
                                                ushort* __restrict__ out,
                                                const int* __restrict__ idg,
                                                const int* __restrict__ eidx, int n) {
    int w = threadIdx.x >> 6, lane = threadIdx.x & 63;
    int i = blockIdx.x * 4 + w;
    if (i >= n) return;
    int q = lane >> 4, sub = lane & 15;          // quarter, 16-B chunk id
    float acc[8] = {};
    if (q == 0) {  // self term once
        uint4 v = *(const uint4*)(g + (size_t)i * 128 + sub * 8);
        acc8(acc, v);
    }
    int deg = idg[i];
    int cnt = min(deg, CAP);
    const int* ep = eidx + (size_t)i * CAP;
    int j = q;
    for (; j + 12 < cnt; j += 16) {
        int sA = clampi(ep[j], n),     sB = clampi(ep[j + 4], n);
        int sC = clampi(ep[j + 8], n), sD = clampi(ep[j + 12], n);
        uint4 vA = *(const uint4*)(g + (size_t)sA * 128 + sub * 8);
        uint4 vB = *(const uint4*)(g + (size_t)sB * 128 + sub * 8);
        uint4 vC = *(const uint4*)(g + (size_t)sC * 128 + sub * 8);
        uint4 vD = *(const uint4*)(g + (size_t)sD * 128 + sub * 8);
        acc8(acc, vA); acc8(acc, vB); acc8(acc, vC); acc8(acc, vD);
    }
    for (; j < cnt; j += 4) {
        int sA = clampi(ep[j], n);
        uint4 vA = *(const uint4*)(g + (size_t)sA * 128 + sub * 8);
        acc8(acc, vA);
    }
#pragma unroll
    for (int d = 0; d < 8; ++d) {
        acc[d] += __shfl_xor(acc[d], 16);
        acc[d] += __shfl_xor(acc[d], 32);
    }
    if (q == 0) {
        float di = rsqrtf((float)(deg + 1));
        uint4 o;
        o.x = (uint)f2bf(acc[0] * di) | ((uint)f2bf(acc[1] * di) << 16);
        o.y = (uint)f2bf(acc[2] * di) | ((uint)f2bf(acc[3] * di) << 16);
        o.z = (uint)f2bf(acc[4] * di) | ((uint)f2bf(acc[5] * di) << 16);
        o.w = (uint)f2bf(acc[6] * di) | ((uint)f2bf(acc[7] * di) << 16);
        *(uint4*)(out + (size_t)i * 128 + sub * 8) = o;
    }
}

// ---------------- agg, 256-dim rows ----------------
__global__ __launch_bounds__(256) void agg256_k(const ushort* __restrict__ g,
                                                ushort* __restrict__ out,
                                                const int* __restrict__ idg,
                                                const int* __restrict__ eidx, int n) {
    int w = threadIdx.x >> 6, lane = threadIdx.x & 63;
    int i = blockIdx.x * 4 + w;
    if (i >= n) return;
    int half = lane >> 5, sub = lane & 31;
    float acc[8] = {};
    if (half == 0) {
        uint4 v = *(const uint4*)(g + (size_t)i * 256 + sub * 8);
        acc8(acc, v);
    }
    int deg = idg[i];
    int cnt = min(deg, CAP);
    const int* ep = eidx + (size_t)i * CAP;
    int j = half;
    for (; j + 6 < cnt; j += 8) {
        int sA = clampi(ep[j], n),     sB = clampi(ep[j + 2], n);
        int sC = clampi(ep[j + 4], n), sD = clampi(ep[j + 6], n);
        uint4 vA = *(const uint4*)(g + (size_t)sA * 256 + sub * 8);
        uint4 vB = *(const uint4*)(g + (size_t)sB * 256 + sub * 8);
        uint4 vC = *(const uint4*)(g + (size_t)sC * 256 + sub * 8);
        uint4 vD = *(const uint4*)(g + (size_t)sD * 256 + sub * 8);
        acc8(acc, vA); acc8(acc, vB); acc8(acc, vC); acc8(acc, vD);
    }
    for (; j < cnt; j += 2) {
        int sA = clampi(ep[j], n);
        uint4 vA = *(const uint4*)(g + (size_t)sA * 256 + sub * 8);
        acc8(acc, vA);
    }
#pragma unroll
    for (int d = 0; d < 8; ++d) acc[d] += __shfl_xor(acc[d], 32);
    if (half == 0) {
        float di = rsqrtf((float)(deg + 1));
        uint4 o;
        o.x = (uint)f2bf(acc[0] * di) | ((uint)f2bf(acc[1] * di) << 16);
        o.y = (uint)f2bf(acc[2] * di) | ((uint)f2bf(acc[3] * di) << 16);
        o.z = (uint)f2bf(acc[4] * di) | ((uint)f2bf(acc[5] * di) << 16);
        o.w = (uint)f2bf(acc[6] * di) | ((uint)f2bf(acc[7] * di) << 16);
        *(uint4*)(out + (size_t)i * 256 + sub * 8) = o;
    }
}

// ---------------- MFMA GEMM, LDS-staged weights (R12, proven) ----------------
template <int K, bool SCALE>
__global__ __launch_bounds__(256) void gemm_ldsw_k(const ushort* __restrict__ A,
                                                   const ushort* __restrict__ Wp,
                                                   const float* __restrict__ bias,
                                                   const int* __restrict__ idg,
                                                   ushort* __restrict__ C, int M) {
    constexpr int S = K / 32;
    constexpr int STAGE_US = 4 * S * 64 * 8;        // ushorts per stage (4 col-tiles)
    __shared__ ushort ldsW[STAGE_US];               // 32 KB (K=256) / 16 KB (K=128)
    int tid = threadIdx.x, wv = tid >> 6, lane = tid & 63;
    int quad = lane >> 4, l15 = lane & 15;
    int rowBase = blockIdx.x * 64 + wv * 16;
    int arow = rowBase + l15; if (arow > M - 1) arow = M - 1;   // clamp (stores guarded)
    const ushort* abase = A + (size_t)arow * K + quad * 8;
    short8 af[S];
#pragma unroll
    for (int s = 0; s < S; ++s) af[s] = *(const short8*)(abase + 32 * s);

    float diRow[4];
    if (SCALE) {
#pragma unroll
        for (int r = 0; r < 4; ++r) {
            int rr = min(rowBase + quad * 4 + r, M - 1);
            diRow[r] = rsqrtf((float)(idg[rr] + 1));
        }
    }

#pragma unroll
    for (int st = 0; st < 4; ++st) {
        __syncthreads();   // previous stage fully consumed before overwrite
        {
            const uint4* src = (const uint4*)(Wp + (size_t)st * STAGE_US);
            uint4* dst = (uint4*)ldsW;
#pragma unroll
            for (int it = 0; it < STAGE_US / 8 / 256; ++it)
                dst[it * 256 + tid] = src[it * 256 + tid];
        }
        __syncthreads();
        float4v acc[4];
#pragma unroll
        for (int nt = 0; nt < 4; ++nt) {
            float4v a = {0.f, 0.f, 0.f, 0.f};
#pragma unroll
            for (int s = 0; s < S; ++s) {
                short8 bf = *(const short8*)&ldsW[((nt * S + s) * 64 + lane) * 8];
                a = __builtin_amdgcn_mfma_f32_16x16x32_bf16(af[s], bf, a, 0, 0, 0);
            }
            acc[nt] = a;
        }
#pragma unroll
        for (int nt = 0; nt < 4; ++nt) {
            int col = (st * 4 + nt) * 16 + l15;
            float b = bias[col];
#pragma unroll
            for (int r = 0; r < 4; ++r) {
                int row = rowBase + quad * 4 + r;
                if (row < M) {
                    float v = fmaxf(acc[nt][r] + b, 0.f);
                    if (SCALE) v *= diRow[r];
                    C[(size_t)row * 256 + col] = f2bf(v);
                }
            }
        }
    }
}

// ---------------- mean pool ----------------
__global__ void pool_k(const ushort* __restrict__ h, const int* __restrict__ batch,
                       float* __restrict__ outsum, int n) {
    int d = threadIdx.x;  // 0..255
    int n0 = blockIdx.x * 128;
    int n1 = min(n0 + 128, n);
    int gcur = -1;
    float sum = 0.f;
    for (int nn = n0; nn < n1; ++nn) {
        int g = batch[nn] & 63;
        float v = bf2f(h[(size_t)nn * 256 + d]);
        if (g != gcur) {
            if (gcur >= 0) atomicAdd(&outsum[gcur * 256 + d], sum);
            gcur = g;
            sum = v;
        } else {
            sum += v;
        }
    }
    if (gcur >= 0) atomicAdd(&outsum[gcur * 256 + d], sum);
}

// ---------------- final: out[g][d] /= count(g), count via inline binary search ----------------
__global__ void final_k(float* __restrict__ out, const int* __restrict__ batch, int n) {
    __shared__ float cntS;
    int g = blockIdx.x, d = threadIdx.x;
    if (d == 0) {
        int lo = 0, hi = n;
        while (lo < hi) { int mid = (lo + hi) >> 1; if (batch[mid] < g) lo = mid + 1; else hi = mid; }
        int s = lo;
        lo = 0; hi = n;
        int g1 = g + 1;
        while (lo < hi) { int mid = (lo + hi) >> 1; if (batch[mid] < g1) lo = mid + 1; else hi = mid; }
        cntS = (float)(lo - s);
    }
    __syncthreads();
    out[g * 256 + d] /= fmaxf(cntS, 1.0f);
}

extern "C" void kernel_launch(void* const* d_in, const int* in_sizes, int n_in,
                              void* d_out, int out_size, void* d_ws, size_t ws_size,
                              hipStream_t stream) {
    const float* x  = (const float*)d_in[0];
    const int*   ei = (const int*)d_in[1];
    const int*   batch = (const int*)d_in[2];
    const float* W1 = (const float*)d_in[3];
    const float* b1 = (const float*)d_in[4];
    const float* W2 = (const float*)d_in[5];
    const float* b2 = (const float*)d_in[6];
    float* out = (float*)d_out;

    const int N  = in_sizes[2];          // 100000
    const int E  = in_sizes[1] / 2;      // 1600000
    const int* row = ei;
    const int* col = ei + E;

    char* p = (char*)d_ws;
    auto alloc = [&](size_t bytes) {
        char* q = p;
        p += (bytes + 255) & ~(size_t)255;
        return q;
    };
    int*    idg    = (int*)alloc((size_t)N * 4);
    int*    eidx   = (int*)alloc((size_t)N * CAP * 4);          // 25.6 MB buckets
    ushort* W1p    = (ushort*)alloc(16 * 4 * 64 * 8 * 2);       // 64 KB
    ushort* W2p    = (ushort*)alloc(16 * 8 * 64 * 8 * 2);       // 128 KB
    ushort* xb     = (ushort*)alloc((size_t)N * 128 * 2);       // bf16 dinv*x
    ushort* aggX   = (ushort*)alloc((size_t)N * 128 * 2);
    ushort* g1     = (ushort*)alloc((size_t)N * 256 * 2);       // dinv*h1
    ushort* aggH   = (ushort*)alloc((size_t)N * 256 * 2);
    ushort* h2     = (ushort*)alloc((size_t)N * 256 * 2);

    const int nbins = (N + NPB - 1) >> 7;                        // 782
    const int nbc   = NCHUNK * nbins;                            // 6256 counters
    int*    binCnt = (int*)alloc((size_t)nbc * 4);               // ~25 KB
    // binBuf (19.2 MB) aliases h2 (51.2 MB): h2 is only written by the layer-2
    // GEMM, long after fill pass 2 has consumed binBuf.
    int2*   binBuf = (int2*)h2;

    const int nb  = (N + 255) / 256;
    const int ebl = (E + 255) / 256;

    zero_all_k<<<nb, 256, 0, stream>>>(idg, out, binCnt, N, out_size, nbc);

    // two-pass XCD-local binned CSR build (replaces single-pass random scatter)
    fillbin1_k<<<ebl, 256, 0, stream>>>(row, col, idg, eidx, binCnt, binBuf, E, nbins);
    fillbin2_k<<<nbins, 512, 0, stream>>>(binCnt, binBuf, idg, eidx, nbins);

    // fused: pack W1 + pack W2 + cvt x->bf16*dinv (dinv inline from idg)
    const int n4 = N * 32;
    prep_k<<<(98304 + n4 + 255) / 256, 256, 0, stream>>>(W1, W1p, W2, W2p, x, idg, xb, n4);

    // layer 1: agg (dinv folded) -> LDS-staged MFMA (epilogue scales by dinv)
    agg128_k<<<(N + 3) / 4, 256, 0, stream>>>(xb, aggX, idg, eidx, N);
    const int gb = (N + 63) / 64;
    gemm_ldsw_k<128, true><<<gb, 256, 0, stream>>>(aggX, W1p, b1, idg, g1, N);

    // layer 2
    agg256_k<<<(N + 3) / 4, 256, 0, stream>>>(g1, aggH, idg, eidx, N);
    gemm_ldsw_k<256, false><<<gb, 256, 0, stream>>>(aggH, W2p, b2, nullptr, h2, N);

    // pool + final
    pool_k<<<(N + 127) / 128, 256, 0, stream>>>(h2, batch, out, N);
    final_k<<<64, 256, 0, stream>>>(out, batch, N);
}

// Round 2
// 540.395 us; speedup vs baseline: 1.0036x; 1.0036x over previous
//
#include <hip/hip_runtime.h>

typedef __attribute__((ext_vector_type(8))) short short8;    // 8 bf16 (4 VGPRs)
typedef __attribute__((ext_vector_type(4))) float float4v;   // 4 fp32 acc

#define CAP 64      // per-node edge bucket capacity (in-degree is Poisson(16), max ~45)
#define NPB 128     // nodes per bin (col-range per pass-2 workgroup)
#define NCHUNK 8    // XCD chunks (blockIdx % 8 ~ XCD round-robin)
#define BINCAP 384  // per-(chunk,bin) capacity: mean 256, sigma 16 -> +8 sigma

__device__ __forceinline__ ushort f2bf(float f) {
    uint u = __float_as_uint(f);
    u += 0x7fffu + ((u >> 16) & 1u);   // round-to-nearest-even
    return (ushort)(u >> 16);
}
__device__ __forceinline__ float bf2f(ushort h) {
    return __uint_as_float((uint)h << 16);
}
__device__ __forceinline__ void acc8(float* acc, uint4 v) {
    acc[0] += __uint_as_float(v.x << 16);
    acc[1] += __uint_as_float(v.x & 0xffff0000u);
    acc[2] += __uint_as_float(v.y << 16);
    acc[3] += __uint_as_float(v.y & 0xffff0000u);
    acc[4] += __uint_as_float(v.z << 16);
    acc[5] += __uint_as_float(v.z & 0xffff0000u);
    acc[6] += __uint_as_float(v.w << 16);
    acc[7] += __uint_as_float(v.w & 0xffff0000u);
}
__device__ __forceinline__ int clampi(int v, int n) {
    return (int)min((uint)v, (uint)(n - 1));
}

// ---------------- zero idg + out + binCnt in one dispatch ----------------
__global__ void zero_all_k(int* __restrict__ idg, float* __restrict__ out,
                           int* __restrict__ binCnt, int n, int nout, int nbc) {
    int i = blockIdx.x * 256 + threadIdx.x;
    if (i < n) idg[i] = 0;
    if (i < nout) out[i] = 0.f;
    if (i < nbc) binCnt[i] = 0;
}

// ---------------- pass 1: XCD-local binning of edges ----------------
__global__ void fillbin1_k(const int* __restrict__ row, const int* __restrict__ col,
                           int* __restrict__ idg, int* __restrict__ eidx,
                           int* __restrict__ binCnt, int2* __restrict__ binBuf,
                           int E, int nbins) {
    int e = blockIdx.x * 256 + threadIdx.x;
    int chunk = blockIdx.x & (NCHUNK - 1);
    if (e < E) {
        int c = col[e], r = row[e];
        int b = c >> 7;                               // c / NPB
        int cell = chunk * nbins + b;
        int p = atomicAdd(&binCnt[cell], 1);
        if (p < BINCAP) {
            binBuf[(size_t)cell * BINCAP + p] = make_int2(r, c);
        } else {                                      // overflow fallback: old direct path
            int q = atomicAdd(&idg[c], 1);
            if (q < CAP) eidx[(size_t)c * CAP + q] = r;
        }
    }
}

// ---------------- pass 2: drain bins -> bucketed CSR, single-L2 scatter ----------------
__global__ __launch_bounds__(512) void fillbin2_k(const int* __restrict__ binCnt,
                                                  const int2* __restrict__ binBuf,
                                                  int* __restrict__ idg,
                                                  int* __restrict__ eidx, int nbins) {
    int bin = blockIdx.x;
    int wv = threadIdx.x >> 6, lane = threadIdx.x & 63;
    int cell = wv * nbins + bin;
    int n = min(binCnt[cell], BINCAP);
    const int2* bp = binBuf + (size_t)cell * BINCAP;
    for (int j = lane; j < n; j += 64) {
        int2 pr = bp[j];
        int c = pr.y;
        int p = atomicAdd(&idg[c], 1);
        if (p < CAP) eidx[(size_t)c * CAP + p] = pr.x;
    }
}

// ---------------- fused: pack W1+W2 to MFMA B-frag order, and x -> bf16*dinv ----------------
__global__ void prep_k(const float* __restrict__ W1, ushort* __restrict__ W1p,
                       const float* __restrict__ W2, ushort* __restrict__ W2p,
                       const float* __restrict__ x, const int* __restrict__ idg,
                       ushort* __restrict__ xb, int n4) {
    int idx = blockIdx.x * 256 + threadIdx.x;
    if (idx < 32768) {                       // pack W1 (S=4)
        int j = idx & 7, lane = (idx >> 3) & 63;
        int s = (idx >> 9) % 4, nt = (idx >> 9) / 4;
        int k = 32 * s + (lane >> 4) * 8 + j;
        int c = nt * 16 + (lane & 15);
        W1p[idx] = f2bf(W1[k * 256 + c]);
    } else if (idx < 32768 + 65536) {        // pack W2 (S=8)
        int q = idx - 32768;
        int j = q & 7, lane = (q >> 3) & 63;
        int s = (q >> 9) % 8, nt = (q >> 9) / 8;
        int k = 32 * s + (lane >> 4) * 8 + j;
        int c = nt * 16 + (lane & 15);
        W2p[q] = f2bf(W2[k * 256 + c]);
    } else {                                 // cvt: x fp32 -> bf16 * dinv
        int i = idx - (32768 + 65536);
        if (i < n4) {
            int node = i >> 5;               // 32 float4 per 128-dim row
            float di = rsqrtf((float)(idg[node] + 1));
            float4 v = ((const float4*)x)[i];
            ushort4 o;
            o.x = f2bf(v.x * di); o.y = f2bf(v.y * di);
            o.z = f2bf(v.z * di); o.w = f2bf(v.w * di);
            ((ushort4*)xb)[i] = o;
        }
    }
}

// ---------------- agg, 128-dim rows: one node per 16-lane quad, deep load batching ----------------
// MLP-first structure: each quad owns a node; 8-deep gather batches -> up to
// 32 independent uint4 loads in flight per wave. No cross-lane reduce needed.
__global__ __launch_bounds__(256) void agg128_k(const ushort* __restrict__ g,
                                                ushort* __restrict__ out,
                                                const int* __restrict__ idg,
                                                const int* __restrict__ eidx, int n) {
    int w = threadIdx.x >> 6, lane = threadIdx.x & 63;
    int q = lane >> 4, sub = lane & 15;
    int i = blockIdx.x * 16 + w * 4 + q;
    if (i >= n) return;
    const ushort* gp = g + (size_t)sub * 8;
    float acc[8] = {};
    {   // self term
        uint4 v = *(const uint4*)(gp + (size_t)i * 128);
        acc8(acc, v);
    }
    int deg = idg[i];
    int cnt = min(deg, CAP);
    const int* ep = eidx + (size_t)i * CAP;
    int j = 0;
    for (; j + 8 <= cnt; j += 8) {
        int s0 = clampi(ep[j], n),     s1 = clampi(ep[j + 1], n);
        int s2 = clampi(ep[j + 2], n), s3 = clampi(ep[j + 3], n);
        int s4 = clampi(ep[j + 4], n), s5 = clampi(ep[j + 5], n);
        int s6 = clampi(ep[j + 6], n), s7 = clampi(ep[j + 7], n);
        uint4 v0 = *(const uint4*)(gp + (size_t)s0 * 128);
        uint4 v1 = *(const uint4*)(gp + (size_t)s1 * 128);
        uint4 v2 = *(const uint4*)(gp + (size_t)s2 * 128);
        uint4 v3 = *(const uint4*)(gp + (size_t)s3 * 128);
        uint4 v4 = *(const uint4*)(gp + (size_t)s4 * 128);
        uint4 v5 = *(const uint4*)(gp + (size_t)s5 * 128);
        uint4 v6 = *(const uint4*)(gp + (size_t)s6 * 128);
        uint4 v7 = *(const uint4*)(gp + (size_t)s7 * 128);
        acc8(acc, v0); acc8(acc, v1); acc8(acc, v2); acc8(acc, v3);
        acc8(acc, v4); acc8(acc, v5); acc8(acc, v6); acc8(acc, v7);
    }
    if (j + 4 <= cnt) {
        int s0 = clampi(ep[j], n),     s1 = clampi(ep[j + 1], n);
        int s2 = clampi(ep[j + 2], n), s3 = clampi(ep[j + 3], n);
        uint4 v0 = *(const uint4*)(gp + (size_t)s0 * 128);
        uint4 v1 = *(const uint4*)(gp + (size_t)s1 * 128);
        uint4 v2 = *(const uint4*)(gp + (size_t)s2 * 128);
        uint4 v3 = *(const uint4*)(gp + (size_t)s3 * 128);
        acc8(acc, v0); acc8(acc, v1); acc8(acc, v2); acc8(acc, v3);
        j += 4;
    }
    if (j + 2 <= cnt) {
        int s0 = clampi(ep[j], n), s1 = clampi(ep[j + 1], n);
        uint4 v0 = *(const uint4*)(gp + (size_t)s0 * 128);
        uint4 v1 = *(const uint4*)(gp + (size_t)s1 * 128);
        acc8(acc, v0); acc8(acc, v1);
        j += 2;
    }
    if (j < cnt) {
        int s0 = clampi(ep[j], n);
        uint4 v0 = *(const uint4*)(gp + (size_t)s0 * 128);
        acc8(acc, v0);
    }
    float di = rsqrtf((float)(deg + 1));
    uint4 o;
    o.x = (uint)f2bf(acc[0] * di) | ((uint)f2bf(acc[1] * di) << 16);
    o.y = (uint)f2bf(acc[2] * di) | ((uint)f2bf(acc[3] * di) << 16);
    o.z = (uint)f2bf(acc[4] * di) | ((uint)f2bf(acc[5] * di) << 16);
    o.w = (uint)f2bf(acc[6] * di) | ((uint)f2bf(acc[7] * di) << 16);
    *(uint4*)(out + (size_t)i * 128 + sub * 8) = o;
}

// ---------------- agg, 256-dim rows: one node per 32-lane half, deep load batching ----------------
__global__ __launch_bounds__(256) void agg256_k(const ushort* __restrict__ g,
                                                ushort* __restrict__ out,
                                                const int* __restrict__ idg,
                                                const int* __restrict__ eidx, int n) {
    int w = threadIdx.x >> 6, lane = threadIdx.x & 63;
    int half = lane >> 5, sub = lane & 31;
    int i = blockIdx.x * 8 + w * 2 + half;
    if (i >= n) return;
    const ushort* gp = g + (size_t)sub * 8;
    float acc[8] = {};
    {   // self term
        uint4 v = *(const uint4*)(gp + (size_t)i * 256);
        acc8(acc, v);
    }
    int deg = idg[i];
    int cnt = min(deg, CAP);
    const int* ep = eidx + (size_t)i * CAP;
    int j = 0;
    for (; j + 8 <= cnt; j += 8) {
        int s0 = clampi(ep[j], n),     s1 = clampi(ep[j + 1], n);
        int s2 = clampi(ep[j + 2], n), s3 = clampi(ep[j + 3], n);
        int s4 = clampi(ep[j + 4], n), s5 = clampi(ep[j + 5], n);
        int s6 = clampi(ep[j + 6], n), s7 = clampi(ep[j + 7], n);
        uint4 v0 = *(const uint4*)(gp + (size_t)s0 * 256);
        uint4 v1 = *(const uint4*)(gp + (size_t)s1 * 256);
        uint4 v2 = *(const uint4*)(gp + (size_t)s2 * 256);
        uint4 v3 = *(const uint4*)(gp + (size_t)s3 * 256);
        uint4 v4 = *(const uint4*)(gp + (size_t)s4 * 256);
        uint4 v5 = *(const uint4*)(gp + (size_t)s5 * 256);
        uint4 v6 = *(const uint4*)(gp + (size_t)s6 * 256);
        uint4 v7 = *(const uint4*)(gp + (size_t)s7 * 256);
        acc8(acc, v0); acc8(acc, v1); acc8(acc, v2); acc8(acc, v3);
        acc8(acc, v4); acc8(acc, v5); acc8(acc, v6); acc8(acc, v7);
    }
    if (j + 4 <= cnt) {
        int s0 = clampi(ep[j], n),     s1 = clampi(ep[j + 1], n);
        int s2 = clampi(ep[j + 2], n), s3 = clampi(ep[j + 3], n);
        uint4 v0 = *(const uint4*)(gp + (size_t)s0 * 256);
        uint4 v1 = *(const uint4*)(gp + (size_t)s1 * 256);
        uint4 v2 = *(const uint4*)(gp + (size_t)s2 * 256);
        uint4 v3 = *(const uint4*)(gp + (size_t)s3 * 256);
        acc8(acc, v0); acc8(acc, v1); acc8(acc, v2); acc8(acc, v3);
        j += 4;
    }
    if (j + 2 <= cnt) {
        int s0 = clampi(ep[j], n), s1 = clampi(ep[j + 1], n);
        uint4 v0 = *(const uint4*)(gp + (size_t)s0 * 256);
        uint4 v1 = *(const uint4*)(gp + (size_t)s1 * 256);
        acc8(acc, v0); acc8(acc, v1);
        j += 2;
    }
    if (j < cnt) {
        int s0 = clampi(ep[j], n);
        uint4 v0 = *(const uint4*)(gp + (size_t)s0 * 256);
        acc8(acc, v0);
    }
    float di = rsqrtf((float)(deg + 1));
    uint4 o;
    o.x = (uint)f2bf(acc[0] * di) | ((uint)f2bf(acc[1] * di) << 16);
    o.y = (uint)f2bf(acc[2] * di) | ((uint)f2bf(acc[3] * di) << 16);
    o.z = (uint)f2bf(acc[4] * di) | ((uint)f2bf(acc[5] * di) << 16);
    o.w = (uint)f2bf(acc[6] * di) | ((uint)f2bf(acc[7] * di) << 16);
    *(uint4*)(out + (size_t)i * 256 + sub * 8) = o;
}

// ---------------- MFMA GEMM, LDS-staged weights (R12, proven) ----------------
template <int K, bool SCALE>
__global__ __launch_bounds__(256) void gemm_ldsw_k(const ushort* __restrict__ A,
                                                   const ushort* __restrict__ Wp,
                                                   const float* __restrict__ bias,
                                                   const int* __restrict__ idg,
                                                   ushort* __restrict__ C, int M) {
    constexpr int S = K / 32;
    constexpr int STAGE_US = 4 * S * 64 * 8;        // ushorts per stage (4 col-tiles)
    __shared__ ushort ldsW[STAGE_US];               // 32 KB (K=256) / 16 KB (K=128)
    int tid = threadIdx.x, wv = tid >> 6, lane = tid & 63;
    int quad = lane >> 4, l15 = lane & 15;
    int rowBase = blockIdx.x * 64 + wv * 16;
    int arow = rowBase + l15; if (arow > M - 1) arow = M - 1;   // clamp (stores guarded)
    const ushort* abase = A + (size_t)arow * K + quad * 8;
    short8 af[S];
#pragma unroll
    for (int s = 0; s < S; ++s) af[s] = *(const short8*)(abase + 32 * s);

    float diRow[4];
    if (SCALE) {
#pragma unroll
        for (int r = 0; r < 4; ++r) {
            int rr = min(rowBase + quad * 4 + r, M - 1);
            diRow[r] = rsqrtf((float)(idg[rr] + 1));
        }
    }

#pragma unroll
    for (int st = 0; st < 4; ++st) {
        __syncthreads();   // previous stage fully consumed before overwrite
        {
            const uint4* src = (const uint4*)(Wp + (size_t)st * STAGE_US);
            uint4* dst = (uint4*)ldsW;
#pragma unroll
            for (int it = 0; it < STAGE_US / 8 / 256; ++it)
                dst[it * 256 + tid] = src[it * 256 + tid];
        }
        __syncthreads();
        float4v acc[4];
#pragma unroll
        for (int nt = 0; nt < 4; ++nt) {
            float4v a = {0.f, 0.f, 0.f, 0.f};
#pragma unroll
            for (int s = 0; s < S; ++s) {
                short8 bf = *(const short8*)&ldsW[((nt * S + s) * 64 + lane) * 8];
                a = __builtin_amdgcn_mfma_f32_16x16x32_bf16(af[s], bf, a, 0, 0, 0);
            }
            acc[nt] = a;
        }
#pragma unroll
        for (int nt = 0; nt < 4; ++nt) {
            int col = (st * 4 + nt) * 16 + l15;
            float b = bias[col];
#pragma unroll
            for (int r = 0; r < 4; ++r) {
                int row = rowBase + quad * 4 + r;
                if (row < M) {
                    float v = fmaxf(acc[nt][r] + b, 0.f);
                    if (SCALE) v *= diRow[r];
                    C[(size_t)row * 256 + col] = f2bf(v);
                }
            }
        }
    }
}

// ---------------- mean pool ----------------
__global__ void pool_k(const ushort* __restrict__ h, const int* __restrict__ batch,
                       float* __restrict__ outsum, int n) {
    int d = threadIdx.x;  // 0..255
    int n0 = blockIdx.x * 128;
    int n1 = min(n0 + 128, n);
    int gcur = -1;
    float sum = 0.f;
    for (int nn = n0; nn < n1; ++nn) {
        int g = batch[nn] & 63;
        float v = bf2f(h[(size_t)nn * 256 + d]);
        if (g != gcur) {
            if (gcur >= 0) atomicAdd(&outsum[gcur * 256 + d], sum);
            gcur = g;
            sum = v;
        } else {
            sum += v;
        }
    }
    if (gcur >= 0) atomicAdd(&outsum[gcur * 256 + d], sum);
}

// ---------------- final: out[g][d] /= count(g), count via inline binary search ----------------
__global__ void final_k(float* __restrict__ out, const int* __restrict__ batch, int n) {
    __shared__ float cntS;
    int g = blockIdx.x, d = threadIdx.x;
    if (d == 0) {
        int lo = 0, hi = n;
        while (lo < hi) { int mid = (lo + hi) >> 1; if (batch[mid] < g) lo = mid + 1; else hi = mid; }
        int s = lo;
        lo = 0; hi = n;
        int g1 = g + 1;
        while (lo < hi) { int mid = (lo + hi) >> 1; if (batch[mid] < g1) lo = mid + 1; else hi = mid; }
        cntS = (float)(lo - s);
    }
    __syncthreads();
    out[g * 256 + d] /= fmaxf(cntS, 1.0f);
}

extern "C" void kernel_launch(void* const* d_in, const int* in_sizes, int n_in,
                              void* d_out, int out_size, void* d_ws, size_t ws_size,
                              hipStream_t stream) {
    const float* x  = (const float*)d_in[0];
    const int*   ei = (const int*)d_in[1];
    const int*   batch = (const int*)d_in[2];
    const float* W1 = (const float*)d_in[3];
    const float* b1 = (const float*)d_in[4];
    const float* W2 = (const float*)d_in[5];
    const float* b2 = (const float*)d_in[6];
    float* out = (float*)d_out;

    const int N  = in_sizes[2];          // 100000
    const int E  = in_sizes[1] / 2;      // 1600000
    const int* row = ei;
    const int* col = ei + E;

    char* p = (char*)d_ws;
    auto alloc = [&](size_t bytes) {
        char* q = p;
        p += (bytes + 255) & ~(size_t)255;
        return q;
    };
    int*    idg    = (int*)alloc((size_t)N * 4);
    int*    eidx   = (int*)alloc((size_t)N * CAP * 4);          // 25.6 MB buckets
    ushort* W1p    = (ushort*)alloc(16 * 4 * 64 * 8 * 2);       // 64 KB
    ushort* W2p    = (ushort*)alloc(16 * 8 * 64 * 8 * 2);       // 128 KB
    ushort* xb     = (ushort*)alloc((size_t)N * 128 * 2);       // bf16 dinv*x
    ushort* aggX   = (ushort*)alloc((size_t)N * 128 * 2);
    ushort* g1     = (ushort*)alloc((size_t)N * 256 * 2);       // dinv*h1
    ushort* aggH   = (ushort*)alloc((size_t)N * 256 * 2);
    ushort* h2     = (ushort*)alloc((size_t)N * 256 * 2);

    const int nbins = (N + NPB - 1) >> 7;                        // 782
    const int nbc   = NCHUNK * nbins;                            // 6256 counters
    int*    binCnt = (int*)alloc((size_t)nbc * 4);               // ~25 KB
    // binBuf (19.2 MB) aliases h2 (51.2 MB): h2 is only written by the layer-2
    // GEMM, long after fill pass 2 has consumed binBuf.
    int2*   binBuf = (int2*)h2;

    const int nb  = (N + 255) / 256;
    const int ebl = (E + 255) / 256;

    zero_all_k<<<nb, 256, 0, stream>>>(idg, out, binCnt, N, out_size, nbc);

    // two-pass XCD-local binned CSR build
    fillbin1_k<<<ebl, 256, 0, stream>>>(row, col, idg, eidx, binCnt, binBuf, E, nbins);
    fillbin2_k<<<nbins, 512, 0, stream>>>(binCnt, binBuf, idg, eidx, nbins);

    // fused: pack W1 + pack W2 + cvt x->bf16*dinv (dinv inline from idg)
    const int n4 = N * 32;
    prep_k<<<(98304 + n4 + 255) / 256, 256, 0, stream>>>(W1, W1p, W2, W2p, x, idg, xb, n4);

    // layer 1: agg (dinv folded) -> LDS-staged MFMA (epilogue scales by dinv)
    agg128_k<<<(N + 15) / 16, 256, 0, stream>>>(xb, aggX, idg, eidx, N);
    const int gb = (N + 63) / 64;
    gemm_ldsw_k<128, true><<<gb, 256, 0, stream>>>(aggX, W1p, b1, idg, g1, N);

    // layer 2
    agg256_k<<<(N + 7) / 8, 256, 0, stream>>>(g1, aggH, idg, eidx, N);
    gemm_ldsw_k<256, false><<<gb, 256, 0, stream>>>(aggH, W2p, b2, nullptr, h2, N);

    // pool + final
    pool_k<<<(N + 127) / 128, 256, 0, stream>>>(h2, batch, out, N);
    final_k<<<64, 256, 0, stream>>>(out, batch, N);
}